// Round 1
// baseline (594.345 us; speedup 1.0000x reference)
//
#include <hip/hip_runtime.h>
#include <hip/hip_bf16.h>
#include <cstdint>

// Problem constants
#define SEQ   2048
#define DMOD  1024
#define QKVD  2048
#define NH    16
#define HDIM  128
#define NTOK  4096   // B*S

typedef __bf16 bf16;
typedef bf16 bf16x4 __attribute__((ext_vector_type(4)));
typedef bf16 bf16x8 __attribute__((ext_vector_type(8)));
typedef float f32x4 __attribute__((ext_vector_type(4)));

typedef __attribute__((address_space(1))) void* as1_t;
typedef __attribute__((address_space(3))) void* as3_t;

__device__ __forceinline__ void gload16(const void* g, void* l) {
  __builtin_amdgcn_global_load_lds((as1_t)(uintptr_t)g, (as3_t)(uintptr_t)l, 16, 0, 0);
}

// ---------------- fp32 -> bf16 cast ----------------
__global__ void cast_f32_bf16(const float* __restrict__ in, bf16* __restrict__ out, int n4) {
  int i = blockIdx.x * blockDim.x + threadIdx.x;
  if (i < n4) {
    float4 v = reinterpret_cast<const float4*>(in)[i];
    bf16x4 o;
    o[0] = (bf16)v.x; o[1] = (bf16)v.y; o[2] = (bf16)v.z; o[3] = (bf16)v.w;
    reinterpret_cast<bf16x4*>(out)[i] = o;
  }
}

// ---------------- GEMM: C[M,N] = A[M,K] @ B[N,K]^T ----------------
// mode 0: bf16 out, row-major [M,N]
// mode 1: bf16 out, V-transposed: out[(b*2048 + col)*2048 + s], token = row = b*2048+s
// mode 2: fp32 out, row-major [M,N]
#define BM 128
#define BN 128
#define BK 64

__global__ __launch_bounds__(256, 2) void gemm_bt_kernel(
    const bf16* __restrict__ A, const bf16* __restrict__ Bw,
    void* __restrict__ Cout, int M, int N, int K, int mode)
{
  __shared__ bf16 As[BM * BK];
  __shared__ bf16 Bs[BN * BK];

  const int tid  = threadIdx.x;
  const int lane = tid & 63;
  const int wid  = tid >> 6;
  const int wr   = wid >> 1;       // wave row (0..1), 64-row strip
  const int wc   = wid & 1;        // wave col (0..1), 64-col strip
  const int lm   = lane & 15;
  const int lg   = lane >> 4;
  const int m0   = blockIdx.y * BM;
  const int n0   = blockIdx.x * BN;

  f32x4 acc[4][4];
#pragma unroll
  for (int i = 0; i < 4; ++i)
#pragma unroll
    for (int j = 0; j < 4; ++j) acc[i][j] = (f32x4)0.0f;

  const int nk = K / BK;

  auto stage = [&](int kt) {
    const int k0 = kt * BK;
    const int rlo = lane >> 3;          // 0..7 row within 8-row chunk
    const int cs  = (lane & 7) * 8;     // col segment (elements)
#pragma unroll
    for (int it = 0; it < 4; ++it) {
      int chunk = wid * 4 + it;         // 0..15, each = 8 rows x 64 cols = 1KB
      int row = chunk * 8 + rlo;
      gload16(A  + (size_t)(m0 + row) * K + k0 + cs, As + chunk * 512);
      gload16(Bw + (size_t)(n0 + row) * K + k0 + cs, Bs + chunk * 512);
    }
  };

  stage(0);
  __syncthreads();

  for (int kt = 0; kt < nk; ++kt) {
#pragma unroll
    for (int kk = 0; kk < 2; ++kk) {
      bf16x8 a[4], b[4];
#pragma unroll
      for (int mi = 0; mi < 4; ++mi)
        a[mi] = *reinterpret_cast<const bf16x8*>(As + (wr * 64 + mi * 16 + lm) * BK + kk * 32 + lg * 8);
#pragma unroll
      for (int ni = 0; ni < 4; ++ni)
        b[ni] = *reinterpret_cast<const bf16x8*>(Bs + (wc * 64 + ni * 16 + lm) * BK + kk * 32 + lg * 8);
#pragma unroll
      for (int mi = 0; mi < 4; ++mi)
#pragma unroll
        for (int ni = 0; ni < 4; ++ni)
          acc[mi][ni] = __builtin_amdgcn_mfma_f32_16x16x32_bf16(a[mi], b[ni], acc[mi][ni], 0, 0, 0);
    }
    __syncthreads();
    if (kt + 1 < nk) stage(kt + 1);
    __syncthreads();
  }

  // epilogue
#pragma unroll
  for (int mi = 0; mi < 4; ++mi) {
#pragma unroll
    for (int ni = 0; ni < 4; ++ni) {
      int col  = n0 + wc * 64 + ni * 16 + lm;
      int row0 = m0 + wr * 64 + mi * 16 + lg * 4;
      f32x4 c = acc[mi][ni];
      if (mode == 0) {
        bf16* Cb = (bf16*)Cout;
#pragma unroll
        for (int r = 0; r < 4; ++r) Cb[(size_t)(row0 + r) * N + col] = (bf16)c[r];
      } else if (mode == 1) {
        bf16* Cb = (bf16*)Cout;
#pragma unroll
        for (int r = 0; r < 4; ++r) {
          int tok = row0 + r; int bb = tok >> 11; int s = tok & 2047;
          Cb[((size_t)bb * QKVD + col) * SEQ + s] = (bf16)c[r];
        }
      } else {
        float* Cf = (float*)Cout;
#pragma unroll
        for (int r = 0; r < 4; ++r) Cf[(size_t)(row0 + r) * N + col] = c[r];
      }
    }
  }
}

// ---------------- Flash attention (causal) ----------------
// Q, K: [NTOK, QKVD] bf16 (token-major). Vt: [(bh*128+d), s] bf16. O: [NTOK, QKVD] bf16.
// Block: 4 waves, each wave owns 16 q-rows. KBLK = 32.
#define QBLK 64

__global__ __launch_bounds__(256, 2) void flash_kernel(
    const bf16* __restrict__ Q, const bf16* __restrict__ Kg,
    const bf16* __restrict__ Vt, bf16* __restrict__ O)
{
  __shared__ bf16 P_lds[4][16 * 40];  // per-wave P tile, stride 40 to dodge bank conflicts

  const int tid  = threadIdx.x;
  const int lane = tid & 63;
  const int wid  = tid >> 6;
  const int lm   = lane & 15;
  const int lg   = lane >> 4;
  const int bh   = blockIdx.y;          // 0..31
  const int b    = bh >> 4;
  const int h    = bh & 15;
  const int q0   = blockIdx.x * QBLK + wid * 16;

  const float sc = 0.08838834764831845f * 1.4426950408889634f; // SCALE * log2(e)

  // Q fragments for this wave's 16 rows (K-contraction dim = HDIM = 4 steps of 32)
  bf16x8 qf[4];
  {
    const bf16* qbase = Q + ((size_t)(b * SEQ + q0 + lm)) * QKVD + h * HDIM + lg * 8;
#pragma unroll
    for (int s4 = 0; s4 < 4; ++s4) qf[s4] = *reinterpret_cast<const bf16x8*>(qbase + s4 * 32);
  }

  f32x4 o[8];
#pragma unroll
  for (int i = 0; i < 8; ++i) o[i] = (f32x4)0.0f;
  float mrow[4], lrow[4];
#pragma unroll
  for (int r = 0; r < 4; ++r) { mrow[r] = -__builtin_inff(); lrow[r] = 0.0f; }

  const int nkt = ((q0 + 15) >> 5) + 1;
  for (int kt = 0; kt < nkt; ++kt) {
    // S = Q K^T  (16 x 32 scores)
    f32x4 sacc[2];
    sacc[0] = (f32x4)0.0f; sacc[1] = (f32x4)0.0f;
#pragma unroll
    for (int nf = 0; nf < 2; ++nf) {
      const bf16* kbase = Kg + ((size_t)(b * SEQ + kt * 32 + nf * 16 + lm)) * QKVD + h * HDIM + lg * 8;
#pragma unroll
      for (int s4 = 0; s4 < 4; ++s4)
        sacc[nf] = __builtin_amdgcn_mfma_f32_16x16x32_bf16(
            qf[s4], *reinterpret_cast<const bf16x8*>(kbase + s4 * 32), sacc[nf], 0, 0, 0);
    }

    const bool full = (kt * 32 + 31) <= q0;   // every key valid for every row of this wave
    float t[2][4];
#pragma unroll
    for (int nf = 0; nf < 2; ++nf)
#pragma unroll
      for (int r = 0; r < 4; ++r) {
        float v = sacc[nf][r] * sc;
        if (!full) {
          int key  = kt * 32 + nf * 16 + lm;
          int qrow = q0 + lg * 4 + r;
          if (key > qrow) v = -1e30f;
        }
        t[nf][r] = v;
      }

    // row max over the 16 lanes of the group
    float mx[4];
#pragma unroll
    for (int r = 0; r < 4; ++r) mx[r] = fmaxf(t[0][r], t[1][r]);
#pragma unroll
    for (int d = 1; d < 16; d <<= 1)
#pragma unroll
      for (int r = 0; r < 4; ++r) mx[r] = fmaxf(mx[r], __shfl_xor(mx[r], d));

    float p[2][4], rs[4];
#pragma unroll
    for (int r = 0; r < 4; ++r) {
      float mn = fmaxf(mrow[r], mx[r]);
      float scale = exp2f(mrow[r] - mn);
      mrow[r] = mn;
      p[0][r] = exp2f(t[0][r] - mn);
      p[1][r] = exp2f(t[1][r] - mn);
      rs[r] = p[0][r] + p[1][r];
      lrow[r] = lrow[r] * scale;
#pragma unroll
      for (int ni = 0; ni < 8; ++ni) o[ni][r] *= scale;
    }
#pragma unroll
    for (int d = 1; d < 16; d <<= 1)
#pragma unroll
      for (int r = 0; r < 4; ++r) rs[r] += __shfl_xor(rs[r], d);
#pragma unroll
    for (int r = 0; r < 4; ++r) lrow[r] += rs[r];

    // P -> LDS (bf16), per-wave buffer
    bf16* pl = &P_lds[wid][0];
#pragma unroll
    for (int nf = 0; nf < 2; ++nf)
#pragma unroll
      for (int r = 0; r < 4; ++r)
        pl[(lg * 4 + r) * 40 + nf * 16 + lm] = (bf16)p[nf][r];

    // P fragment (A operand: 16 q-rows x 32 keys)
    bf16x8 pa = *reinterpret_cast<const bf16x8*>(pl + lm * 40 + lg * 8);

    // O += P @ V  (V consumed from transposed layout, contiguous along s)
    const bf16* vb = Vt + ((size_t)bh * HDIM + lm) * SEQ + kt * 32 + lg * 8;
#pragma unroll
    for (int ni = 0; ni < 8; ++ni)
      o[ni] = __builtin_amdgcn_mfma_f32_16x16x32_bf16(
          pa, *reinterpret_cast<const bf16x8*>(vb + (size_t)ni * 16 * SEQ), o[ni], 0, 0, 0);
  }

  // epilogue: O[token][h*128 + d] = o / l
#pragma unroll
  for (int ni = 0; ni < 8; ++ni)
#pragma unroll
    for (int r = 0; r < 4; ++r)
      O[((size_t)(b * SEQ + q0 + lg * 4 + r)) * QKVD + h * HDIM + ni * 16 + lm] =
          (bf16)(o[ni][r] / lrow[r]);
}

// ---------------- launch ----------------
extern "C" void kernel_launch(void* const* d_in, const int* in_sizes, int n_in,
                              void* d_out, int out_size, void* d_ws, size_t ws_size,
                              hipStream_t stream) {
  const float* x  = (const float*)d_in[0];
  const float* wq = (const float*)d_in[1];
  const float* wk = (const float*)d_in[2];
  const float* wv = (const float*)d_in[3];
  const float* wo = (const float*)d_in[4];
  float* out = (float*)d_out;

  bf16* xb  = (bf16*)d_ws;                 // 4096x1024
  bf16* wqb = xb  + (size_t)NTOK * DMOD;   // 2048x1024
  bf16* wkb = wqb + (size_t)QKVD * DMOD;
  bf16* wvb = wkb + (size_t)QKVD * DMOD;
  bf16* wob = wvb + (size_t)QKVD * DMOD;   // 1024x2048
  bf16* Qb  = wob + (size_t)DMOD * QKVD;   // 4096x2048
  bf16* Kb  = Qb  + (size_t)NTOK * QKVD;
  bf16* Vtb = Kb  + (size_t)NTOK * QKVD;
  bf16* Ob  = Vtb + (size_t)NTOK * QKVD;

  // casts
  cast_f32_bf16<<<(NTOK * DMOD / 4) / 256, 256, 0, stream>>>(x,  xb,  NTOK * DMOD / 4);
  cast_f32_bf16<<<(QKVD * DMOD / 4) / 256, 256, 0, stream>>>(wq, wqb, QKVD * DMOD / 4);
  cast_f32_bf16<<<(QKVD * DMOD / 4) / 256, 256, 0, stream>>>(wk, wkb, QKVD * DMOD / 4);
  cast_f32_bf16<<<(QKVD * DMOD / 4) / 256, 256, 0, stream>>>(wv, wvb, QKVD * DMOD / 4);
  cast_f32_bf16<<<(DMOD * QKVD / 4) / 256, 256, 0, stream>>>(wo, wob, DMOD * QKVD / 4);

  // QKV projections: [4096,1024] @ [2048,1024]^T -> [4096,2048]
  dim3 gqkv(QKVD / BN, NTOK / BM);
  gemm_bt_kernel<<<gqkv, 256, 0, stream>>>(xb, wqb, Qb,  NTOK, QKVD, DMOD, 0);
  gemm_bt_kernel<<<gqkv, 256, 0, stream>>>(xb, wkb, Kb,  NTOK, QKVD, DMOD, 0);
  gemm_bt_kernel<<<gqkv, 256, 0, stream>>>(xb, wvb, Vtb, NTOK, QKVD, DMOD, 1);

  // attention
  flash_kernel<<<dim3(SEQ / QBLK, 32), 256, 0, stream>>>(Qb, Kb, Vtb, Ob);

  // output projection: [4096,2048] @ [1024,2048]^T -> [4096,1024] fp32
  dim3 gout(DMOD / BN, NTOK / BM);
  gemm_bt_kernel<<<gout, 256, 0, stream>>>(Ob, wob, out, NTOK, DMOD, QKVD, 2);
}

// Round 2
// 319.289 us; speedup vs baseline: 1.8615x; 1.8615x over previous
//
#include <hip/hip_runtime.h>
#include <hip/hip_bf16.h>
#include <cstdint>

// Problem constants
#define SEQ   2048
#define DMOD  1024
#define QKVD  2048
#define NH    16
#define HDIM  128
#define NTOK  4096   // B*S

typedef __bf16 bf16;
typedef bf16 bf16x4 __attribute__((ext_vector_type(4)));
typedef bf16 bf16x8 __attribute__((ext_vector_type(8)));
typedef float f32x4 __attribute__((ext_vector_type(4)));

typedef __attribute__((address_space(1))) void* as1_t;
typedef __attribute__((address_space(3))) void* as3_t;

__device__ __forceinline__ void gload16(const void* g, void* l) {
  __builtin_amdgcn_global_load_lds((as1_t)(uintptr_t)g, (as3_t)(uintptr_t)l, 16, 0, 0);
}

// ---------------- fp32 -> bf16 cast ----------------
__global__ void cast_f32_bf16(const float* __restrict__ in, bf16* __restrict__ out, int n4) {
  int i = blockIdx.x * blockDim.x + threadIdx.x;
  if (i < n4) {
    float4 v = reinterpret_cast<const float4*>(in)[i];
    bf16x4 o;
    o[0] = (bf16)v.x; o[1] = (bf16)v.y; o[2] = (bf16)v.z; o[3] = (bf16)v.w;
    reinterpret_cast<bf16x4*>(out)[i] = o;
  }
}

// ---------------- GEMM: C[M,N] = A[M,K] @ B[N,K]^T ----------------
// mode 0: bf16 out, row-major [M,N]
// mode 1: bf16 out, V-transposed: out[(b*2048 + col)*2048 + s], token = row = b*2048+s
// mode 2: fp32 out, row-major [M,N]
#define BM 128
#define BN 128
#define BK 64

__global__ __launch_bounds__(256, 2) void gemm_bt_kernel(
    const bf16* __restrict__ A, const bf16* __restrict__ Bw,
    void* __restrict__ Cout, int M, int N, int K, int mode)
{
  __shared__ bf16 As[BM * BK];
  __shared__ bf16 Bs[BN * BK];

  const int tid  = threadIdx.x;
  const int lane = tid & 63;
  const int wid  = tid >> 6;
  const int wr   = wid >> 1;       // wave row (0..1), 64-row strip
  const int wc   = wid & 1;        // wave col (0..1), 64-col strip
  const int lm   = lane & 15;
  const int lg   = lane >> 4;
  const int m0   = blockIdx.y * BM;
  const int n0   = blockIdx.x * BN;

  f32x4 acc[4][4];
#pragma unroll
  for (int i = 0; i < 4; ++i)
#pragma unroll
    for (int j = 0; j < 4; ++j) acc[i][j] = (f32x4)0.0f;

  const int nk = K / BK;

  auto stage = [&](int kt) {
    const int k0 = kt * BK;
    const int rlo = lane >> 3;          // 0..7 row within 8-row chunk
    const int cs  = (lane & 7) * 8;     // col segment (elements)
#pragma unroll
    for (int it = 0; it < 4; ++it) {
      int chunk = wid * 4 + it;         // 0..15, each = 8 rows x 64 cols = 1KB
      int row = chunk * 8 + rlo;
      gload16(A  + (size_t)(m0 + row) * K + k0 + cs, As + chunk * 512);
      gload16(Bw + (size_t)(n0 + row) * K + k0 + cs, Bs + chunk * 512);
    }
  };

  stage(0);
  __syncthreads();

  for (int kt = 0; kt < nk; ++kt) {
#pragma unroll
    for (int kk = 0; kk < 2; ++kk) {
      bf16x8 a[4], b[4];
#pragma unroll
      for (int mi = 0; mi < 4; ++mi)
        a[mi] = *reinterpret_cast<const bf16x8*>(As + (wr * 64 + mi * 16 + lm) * BK + kk * 32 + lg * 8);
#pragma unroll
      for (int ni = 0; ni < 4; ++ni)
        b[ni] = *reinterpret_cast<const bf16x8*>(Bs + (wc * 64 + ni * 16 + lm) * BK + kk * 32 + lg * 8);
#pragma unroll
      for (int mi = 0; mi < 4; ++mi)
#pragma unroll
        for (int ni = 0; ni < 4; ++ni)
          acc[mi][ni] = __builtin_amdgcn_mfma_f32_16x16x32_bf16(a[mi], b[ni], acc[mi][ni], 0, 0, 0);
    }
    __syncthreads();
    if (kt + 1 < nk) stage(kt + 1);
    __syncthreads();
  }

  // epilogue
#pragma unroll
  for (int mi = 0; mi < 4; ++mi) {
#pragma unroll
    for (int ni = 0; ni < 4; ++ni) {
      int col  = n0 + wc * 64 + ni * 16 + lm;
      int row0 = m0 + wr * 64 + mi * 16 + lg * 4;
      f32x4 c = acc[mi][ni];
      if (mode == 0) {
        bf16* Cb = (bf16*)Cout;
#pragma unroll
        for (int r = 0; r < 4; ++r) Cb[(size_t)(row0 + r) * N + col] = (bf16)c[r];
      } else if (mode == 1) {
        bf16* Cb = (bf16*)Cout;
#pragma unroll
        for (int r = 0; r < 4; ++r) {
          int tok = row0 + r; int bb = tok >> 11; int s = tok & 2047;
          Cb[((size_t)bb * QKVD + col) * SEQ + s] = (bf16)c[r];
        }
      } else {
        float* Cf = (float*)Cout;
#pragma unroll
        for (int r = 0; r < 4; ++r) Cf[(size_t)(row0 + r) * N + col] = c[r];
      }
    }
  }
}

// ---------------- Flash attention (causal), LDS-staged, double-buffered ----------------
// Q, K: [NTOK, QKVD] bf16. Vt: [(bh*128+d), s] bf16. O: [NTOK, QKVD] bf16.
// Block: 4 waves, 128 q-rows/block; wave owns rows {rA..rA+15} and {rA+64..rA+79}.
// KBLK = 64 keys/iter. K-tile [64 keys][128 d] and Vt-tile [128 d][64 s] staged in LDS,
// XOR-swizzled (byte ^= (row&7)<<4) with inverse-swizzled global source (rule #21).
#define QBLK 128

__global__ __launch_bounds__(256, 2) void flash_kernel(
    const bf16* __restrict__ Q, const bf16* __restrict__ Kg,
    const bf16* __restrict__ Vt, bf16* __restrict__ O)
{
  __shared__ bf16 KV[2][16384];      // per buf: K 64x128 (8192) | Vt 128x64 (8192) = 32KB
  __shared__ bf16 Pl[4][2][1024];    // per wave, per m-frag: 16 rows x 64 keys, swizzled

  const int tid  = threadIdx.x;
  const int lane = tid & 63;
  const int wid  = tid >> 6;
  const int lm   = lane & 15;
  const int lg   = lane >> 4;
  const int bh   = blockIdx.y;          // 0..31
  const int b    = bh >> 4;
  const int h    = bh & 15;
  const int bx   = (int)(gridDim.x - 1 - blockIdx.x);  // LPT: heaviest q-tiles first
  const int rA   = bx * QBLK + wid * 16;
  const int rB   = rA + 64;
  const int nkt  = 2 * bx + 2;

  const float sc = 0.08838834764831845f * 1.4426950408889634f; // SCALE * log2(e)

  // Q fragments (2 m-frags x 4 k-steps), held in registers
  bf16x8 qf[2][4];
#pragma unroll
  for (int m = 0; m < 2; ++m) {
    const bf16* qb = Q + ((size_t)(b * SEQ + rA + m * 64 + lm)) * QKVD + h * HDIM + lg * 8;
#pragma unroll
    for (int s4 = 0; s4 < 4; ++s4) qf[m][s4] = *reinterpret_cast<const bf16x8*>(qb + s4 * 32);
  }

  f32x4 o[2][8];
#pragma unroll
  for (int m = 0; m < 2; ++m)
#pragma unroll
    for (int i = 0; i < 8; ++i) o[m][i] = (f32x4)0.0f;
  float mrow[2][4], lrow[2][4];
#pragma unroll
  for (int m = 0; m < 2; ++m)
#pragma unroll
    for (int r = 0; r < 4; ++r) { mrow[m][r] = -__builtin_inff(); lrow[m][r] = 0.0f; }

  auto stage = [&](int kt, int buf) {
    bf16* kb = &KV[buf][0];
    bf16* vb = &KV[buf][8192];
    const int rb0 = wid * 16;
#pragma unroll
    for (int i = 0; i < 4; ++i) {              // 4 rows x 256B per op
      int r0 = rb0 + i * 4;
      int r  = r0 + (lane >> 4);
      int c  = ((lane & 15) * 16) ^ ((r & 7) << 4);   // inverse-swizzled source byte
      gload16(Kg + ((size_t)(b * SEQ + kt * 64 + r)) * QKVD + h * HDIM + (c >> 1),
              kb + r0 * 128);
    }
    const int db0 = wid * 32;
#pragma unroll
    for (int i = 0; i < 4; ++i) {              // 8 d-rows x 128B per op
      int d0 = db0 + i * 8;
      int d  = d0 + (lane >> 3);
      int c  = ((lane & 7) * 16) ^ ((d & 7) << 4);
      gload16(Vt + ((size_t)(bh * HDIM + d)) * SEQ + kt * 64 + (c >> 1),
              vb + d0 * 64);
    }
  };

  stage(0, 0);
  __syncthreads();

  int cur = 0;
  for (int kt = 0; kt < nkt; ++kt) {
    if (kt + 1 < nkt) stage(kt + 1, cur ^ 1);

    const char* kbb = (const char*)&KV[cur][0];
    const char* vbb = kbb + 16384;
    const bool act0 = kt * 64 <= rA + 15;
    const bool act1 = kt * 64 <= rB + 15;

    // ---- QK^T: K fragments shared by both m-frags ----
    f32x4 sa[2][4];
#pragma unroll
    for (int m = 0; m < 2; ++m)
#pragma unroll
      for (int nf = 0; nf < 4; ++nf) sa[m][nf] = (f32x4)0.0f;

#pragma unroll
    for (int nf = 0; nf < 4; ++nf) {
      const int j = nf * 16 + lm;
      const char* krow = kbb + j * 256;
      const int jx = (j & 7) << 4;
      bf16x8 kf[4];
#pragma unroll
      for (int s4 = 0; s4 < 4; ++s4)
        kf[s4] = *(const bf16x8*)(krow + ((s4 * 64 + lg * 16) ^ jx));
      if (act0) {
#pragma unroll
        for (int s4 = 0; s4 < 4; ++s4)
          sa[0][nf] = __builtin_amdgcn_mfma_f32_16x16x32_bf16(qf[0][s4], kf[s4], sa[0][nf], 0, 0, 0);
      }
      if (act1) {
#pragma unroll
        for (int s4 = 0; s4 < 4; ++s4)
          sa[1][nf] = __builtin_amdgcn_mfma_f32_16x16x32_bf16(qf[1][s4], kf[s4], sa[1][nf], 0, 0, 0);
      }
    }

    // ---- softmax + P store, per active m-frag ----
#pragma unroll
    for (int m = 0; m < 2; ++m) {
      if (!(m ? act1 : act0)) continue;
      const int rf = rA + m * 64;
      const bool full = (kt * 64 + 63) <= rf;
      float t[4][4];
#pragma unroll
      for (int nf = 0; nf < 4; ++nf)
#pragma unroll
        for (int r = 0; r < 4; ++r) {
          float v = sa[m][nf][r] * sc;
          if (!full) {
            int key = kt * 64 + nf * 16 + lm;
            if (key > rf + lg * 4 + r) v = -1e30f;
          }
          t[nf][r] = v;
        }
      float mx[4];
#pragma unroll
      for (int r = 0; r < 4; ++r)
        mx[r] = fmaxf(fmaxf(t[0][r], t[1][r]), fmaxf(t[2][r], t[3][r]));
#pragma unroll
      for (int d = 1; d < 16; d <<= 1)
#pragma unroll
        for (int r = 0; r < 4; ++r) mx[r] = fmaxf(mx[r], __shfl_xor(mx[r], d));

      float p[4][4], rs[4], scl[4];
#pragma unroll
      for (int r = 0; r < 4; ++r) {
        float mn = fmaxf(mrow[m][r], mx[r]);
        scl[r] = exp2f(mrow[m][r] - mn);
        mrow[m][r] = mn;
#pragma unroll
        for (int nf = 0; nf < 4; ++nf) p[nf][r] = exp2f(t[nf][r] - mn);
        rs[r] = (p[0][r] + p[1][r]) + (p[2][r] + p[3][r]);
#pragma unroll
        for (int ni = 0; ni < 8; ++ni) o[m][ni][r] *= scl[r];
      }
#pragma unroll
      for (int d = 1; d < 16; d <<= 1)
#pragma unroll
        for (int r = 0; r < 4; ++r) rs[r] += __shfl_xor(rs[r], d);
#pragma unroll
      for (int r = 0; r < 4; ++r) lrow[m][r] = lrow[m][r] * scl[r] + rs[r];

      char* pb = (char*)&Pl[wid][m][0];
#pragma unroll
      for (int nf = 0; nf < 4; ++nf)
#pragma unroll
        for (int r = 0; r < 4; ++r) {
          int row = lg * 4 + r;
          *(bf16*)(pb + row * 128 + ((nf * 32 + lm * 2) ^ ((row & 7) << 4))) = (bf16)p[nf][r];
        }
    }

    // ---- PV: V fragments shared by both m-frags ----
#pragma unroll
    for (int kk = 0; kk < 2; ++kk) {
      bf16x8 pa[2];
      if (act0) pa[0] = *(const bf16x8*)((const char*)&Pl[wid][0][0] + lm * 128 + ((kk * 64 + lg * 16) ^ ((lm & 7) << 4)));
      if (act1) pa[1] = *(const bf16x8*)((const char*)&Pl[wid][1][0] + lm * 128 + ((kk * 64 + lg * 16) ^ ((lm & 7) << 4)));
#pragma unroll
      for (int ni = 0; ni < 8; ++ni) {
        const int d = ni * 16 + lm;
        bf16x8 vf = *(const bf16x8*)(vbb + d * 128 + ((kk * 64 + lg * 16) ^ ((d & 7) << 4)));
        if (act0) o[0][ni] = __builtin_amdgcn_mfma_f32_16x16x32_bf16(pa[0], vf, o[0][ni], 0, 0, 0);
        if (act1) o[1][ni] = __builtin_amdgcn_mfma_f32_16x16x32_bf16(pa[1], vf, o[1][ni], 0, 0, 0);
      }
    }

    __syncthreads();
    cur ^= 1;
  }

  // epilogue
#pragma unroll
  for (int m = 0; m < 2; ++m)
#pragma unroll
    for (int ni = 0; ni < 8; ++ni)
#pragma unroll
      for (int r = 0; r < 4; ++r)
        O[((size_t)(b * SEQ + rA + m * 64 + lg * 4 + r)) * QKVD + h * HDIM + ni * 16 + lm] =
            (bf16)(o[m][ni][r] / lrow[m][r]);
}

// ---------------- launch ----------------
extern "C" void kernel_launch(void* const* d_in, const int* in_sizes, int n_in,
                              void* d_out, int out_size, void* d_ws, size_t ws_size,
                              hipStream_t stream) {
  const float* x  = (const float*)d_in[0];
  const float* wq = (const float*)d_in[1];
  const float* wk = (const float*)d_in[2];
  const float* wv = (const float*)d_in[3];
  const float* wo = (const float*)d_in[4];
  float* out = (float*)d_out;

  bf16* xb  = (bf16*)d_ws;                 // 4096x1024
  bf16* wqb = xb  + (size_t)NTOK * DMOD;   // 2048x1024
  bf16* wkb = wqb + (size_t)QKVD * DMOD;
  bf16* wvb = wkb + (size_t)QKVD * DMOD;
  bf16* wob = wvb + (size_t)QKVD * DMOD;   // 1024x2048
  bf16* Qb  = wob + (size_t)DMOD * QKVD;   // 4096x2048
  bf16* Kb  = Qb  + (size_t)NTOK * QKVD;
  bf16* Vtb = Kb  + (size_t)NTOK * QKVD;
  bf16* Ob  = Vtb + (size_t)NTOK * QKVD;

  // casts
  cast_f32_bf16<<<(NTOK * DMOD / 4) / 256, 256, 0, stream>>>(x,  xb,  NTOK * DMOD / 4);
  cast_f32_bf16<<<(QKVD * DMOD / 4) / 256, 256, 0, stream>>>(wq, wqb, QKVD * DMOD / 4);
  cast_f32_bf16<<<(QKVD * DMOD / 4) / 256, 256, 0, stream>>>(wk, wkb, QKVD * DMOD / 4);
  cast_f32_bf16<<<(QKVD * DMOD / 4) / 256, 256, 0, stream>>>(wv, wvb, QKVD * DMOD / 4);
  cast_f32_bf16<<<(DMOD * QKVD / 4) / 256, 256, 0, stream>>>(wo, wob, DMOD * QKVD / 4);

  // QKV projections: [4096,1024] @ [2048,1024]^T -> [4096,2048]
  dim3 gqkv(QKVD / BN, NTOK / BM);
  gemm_bt_kernel<<<gqkv, 256, 0, stream>>>(xb, wqb, Qb,  NTOK, QKVD, DMOD, 0);
  gemm_bt_kernel<<<gqkv, 256, 0, stream>>>(xb, wkb, Kb,  NTOK, QKVD, DMOD, 0);
  gemm_bt_kernel<<<gqkv, 256, 0, stream>>>(xb, wvb, Vtb, NTOK, QKVD, DMOD, 1);

  // attention
  flash_kernel<<<dim3(SEQ / QBLK, 32), 256, 0, stream>>>(Qb, Kb, Vtb, Ob);

  // output projection: [4096,2048] @ [1024,2048]^T -> [4096,1024] fp32
  dim3 gout(DMOD / BN, NTOK / BM);
  gemm_bt_kernel<<<gout, 256, 0, stream>>>(Ob, wob, out, NTOK, DMOD, QKVD, 2);
}